// Round 7
// baseline (306.915 us; speedup 1.0000x reference)
//
#include <hip/hip_runtime.h>
#include <math.h>

#define D 128
#define HD 256
#define N_ENT 100000
#define NBATCH 64
#define NTOT (N_ENT + NBATCH)   // 100064
#define RCOUNT 500
#define E_BASE 400000
#define ETOT (E_BASE + N_ENT)   // 500000
#define NEG 0.2f
#define ZERO_NB 391             // 391*256 = 100096 (cnt padded)
#define CPAD (ZERO_NB * 256)
#define SLOTS 64                // bucket slots per target; P(Poisson(5)>63) ~ 1e-44

#define WCAST_NB 64
#define REL_NB (RCOUNT + 1)
#define PREP_NB (WCAST_NB + ZERO_NB + REL_NB)   // 956

#define GEMM_NB ((NTOT + 63) / 64)              // 1564
#define APP_NB ((ETOT + 255) / 256)             // 1954

typedef __attribute__((ext_vector_type(8))) short bf16x8;
typedef __attribute__((ext_vector_type(8))) unsigned short u16x8;
typedef __attribute__((ext_vector_type(4))) float f32x4;

static __device__ __forceinline__ unsigned short f2bf(float f) {
  unsigned u = __builtin_bit_cast(unsigned, f);
  u += 0x7fffu + ((u >> 16) & 1u);   // RNE
  return (unsigned short)(u >> 16);
}
static __device__ __forceinline__ float bf2f(unsigned short h) {
  return __builtin_bit_cast(float, (unsigned)h << 16);
}

// ---------------- prep: Wbf cast | zero cnt | e_rel + out_edge ----------------
__global__ __launch_bounds__(256) void k_prep(
    const float* __restrict__ W_l, const float* __restrict__ W_r,
    unsigned short* __restrict__ Wbf,
    const float* __restrict__ relations, const float* __restrict__ W_ea,
    const float* __restrict__ W_le, const float* __restrict__ b_le,
    unsigned short* __restrict__ e_rel, float* __restrict__ out_edge,
    int* __restrict__ cnt) {
  __shared__ float relu_p[HD];
  int bx = blockIdx.x;
  int tid = threadIdx.x;
  if (bx < WCAST_NB) {
    int e4 = (bx * 256 + tid) * 4;
    int v = e4 >> 7;          // virtual row 0..511
    int k = e4 & 127;
    const float* src = (v < HD) ? (W_l + (size_t)v * D + k) : (W_r + (size_t)(v - HD) * D + k);
    float4 a = *(const float4*)src;
    *(ushort4*)(Wbf + (size_t)v * D + k) = make_ushort4(f2bf(a.x), f2bf(a.y), f2bf(a.z), f2bf(a.w));
    return;
  }
  if (bx < WCAST_NB + ZERO_NB) {
    cnt[(bx - WCAST_NB) * 256 + tid] = 0;
    return;
  }
  int r = bx - (WCAST_NB + ZERO_NB);   // 0..500
  int j = tid;
  const float* w = W_ea + (size_t)j * D;
  float acc = 0.f;
  if (r < RCOUNT) {
    const float* rel = relations + (size_t)r * D;
    for (int k = 0; k < D; k += 4) {
      float4 a = *(const float4*)(rel + k);
      float4 b = *(const float4*)(w + k);
      acc += a.x * b.x + a.y * b.y + a.z * b.z + a.w * b.w;
    }
  } else {  // all-ones rel_feat row -> row sums of W_ea
    for (int k = 0; k < D; k += 4) {
      float4 b = *(const float4*)(w + k);
      acc += b.x + b.y + b.z + b.w;
    }
  }
  e_rel[(size_t)r * HD + j] = f2bf(acc);
  if (r < RCOUNT) {
    relu_p[j] = acc > 0.f ? acc : 0.f;
    __syncthreads();
    if (j < D) {
      const float* wl = W_le + (size_t)j * HD;
      float o = b_le[j];
      for (int k = 0; k < HD; k += 4) {
        float4 p4 = *(const float4*)(relu_p + k);
        float4 w4 = *(const float4*)(wl + k);
        o += p4.x * w4.x + p4.y * w4.y + p4.z * w4.z + p4.w * w4.w;
      }
      out_edge[(size_t)r * D + j] = o;
    }
  }
}

// ---------------- MFMA GEMM (A-frags in registers, no A-LDS) + bucket append ----------------
#define LDA 136  // Cs LDS row stride in ushort

__global__ __launch_bounds__(256) void k_gemm_mfma(
    const float* __restrict__ entities, const float* __restrict__ queries,
    const unsigned short* __restrict__ Wbf,
    const float* __restrict__ b_l, const float* __restrict__ b_r,
    unsigned short* __restrict__ x_l, unsigned short* __restrict__ x_r,
    const int* __restrict__ edge_index, const int* __restrict__ relation_index,
    const int* __restrict__ batch, int* __restrict__ cnt,
    unsigned int* __restrict__ bucket) {
  __shared__ unsigned short Cs[64 * LDA];
  int tid = threadIdx.x;
  if (blockIdx.x >= GEMM_NB) {   // bucket-append blocks (replaces hist+scan+scatter)
    int e = (blockIdx.x - GEMM_NB) * 256 + tid;
    if (e < ETOT) {
      int s, t, r;
      if (e < E_BASE) {
        s = edge_index[e];
        t = edge_index[E_BASE + e];
        r = relation_index[e];
      } else {
        int i = e - E_BASE;
        s = N_ENT + batch[i];
        t = i;
        r = RCOUNT;
      }
      int pos = atomicAdd(cnt + t, 1);
      if (pos < SLOTS) bucket[(size_t)t * SLOTS + pos] = (unsigned)s | ((unsigned)r << 17);
    }
    return;
  }
  int rb = blockIdx.x;          // 64-row tile

  int w = tid >> 6, lane = tid & 63;
  int wr = w >> 1, wc = w & 1;          // 2x2 wave grid per 128-col chunk
  int m = lane & 15, q8 = (lane >> 4) * 8;

  // ---- load this wave's A fragments once (registers), reused for all 4 col chunks ----
  bf16x8 af[2][4];
#pragma unroll
  for (int i = 0; i < 2; i++) {
    int row = rb * 64 + wr * 32 + i * 16 + m;
    if (row >= NTOT) row = 0;  // stores guarded later
    const float* sp = (row < N_ENT) ? (entities + (size_t)row * D)
                                    : (queries + (size_t)(row - N_ENT) * D);
#pragma unroll
    for (int kk = 0; kk < 4; kk++) {
      float4 a0 = *(const float4*)(sp + kk * 32 + q8);
      float4 a1 = *(const float4*)(sp + kk * 32 + q8 + 4);
      bf16x8 v;
      v[0] = f2bf(a0.x); v[1] = f2bf(a0.y); v[2] = f2bf(a0.z); v[3] = f2bf(a0.w);
      v[4] = f2bf(a1.x); v[5] = f2bf(a1.y); v[6] = f2bf(a1.z); v[7] = f2bf(a1.w);
      af[i][kk] = v;
    }
  }

  for (int ccv = 0; ccv < 4; ccv++) {   // 128-vcol chunks (0,1->x_l; 2,3->x_r)
    bool isL = ccv < 2;
    const float* bv = isL ? b_l : b_r;
    unsigned short* xdst = isL ? x_l : x_r;
    int cbase = (ccv & 1) * 128;

    f32x4 acc[2][4];
#pragma unroll
    for (int i = 0; i < 2; i++)
#pragma unroll
      for (int j = 0; j < 4; j++) acc[i][j] = (f32x4){0.f, 0.f, 0.f, 0.f};

    const unsigned short* wb0 = Wbf + (size_t)(ccv * 128 + wc * 64 + m) * D + q8;
#pragma unroll
    for (int kk = 0; kk < 4; kk++) {
      bf16x8 bfr[4];
#pragma unroll
      for (int j = 0; j < 4; j++)
        bfr[j] = *(const bf16x8*)(wb0 + (size_t)j * 16 * D + kk * 32);
#pragma unroll
      for (int i = 0; i < 2; i++)
#pragma unroll
        for (int j = 0; j < 4; j++)
          acc[i][j] = __builtin_amdgcn_mfma_f32_16x16x32_bf16(af[i][kk], bfr[j], acc[i][j], 0, 0, 0);
    }

    __syncthreads();  // prior chunk's Cs reads complete
    // acc -> Cs (row-major, +bias, bf16). C layout: col=lane&15, row=(lane>>4)*4+reg
#pragma unroll
    for (int j = 0; j < 4; j++) {
      int col = wc * 64 + j * 16 + m;
      float bb = bv[cbase + col];
#pragma unroll
      for (int i = 0; i < 2; i++) {
        int row0 = wr * 32 + i * 16 + (lane >> 4) * 4;
#pragma unroll
        for (int r = 0; r < 4; r++)
          Cs[(row0 + r) * LDA + col] = f2bf(acc[i][j][r] + bb);
      }
    }
    __syncthreads();
    // coalesced global store: 64 rows x 128 cols bf16, 16B/thread-iter
#pragma unroll
    for (int it = 0; it < 4; it++) {
      int g = it * 256 + tid;
      int row = g >> 4, c8 = (g & 15) * 8;
      int grow = rb * 64 + row;
      if (grow < NTOT) {
        u16x8 v = *(const u16x8*)(&Cs[row * LDA + c8]);
        *(u16x8*)(xdst + (size_t)grow * HD + cbase + c8) = v;
      }
    }
  }
}

// ---------------- per-target aggregate: 2 edges/wave-iter, 8 elems/lane (R4 shape) ----------------
// lanes 0-31 edge e, lanes 32-63 edge e+1; sl 0-15 head0, sl 16-31 head1.
__global__ __launch_bounds__(256) void k_edge(
    const unsigned short* __restrict__ x_l, const unsigned short* __restrict__ x_r,
    const unsigned short* __restrict__ e_rel, const int* __restrict__ cnt,
    const unsigned int* __restrict__ bucket, const float* __restrict__ att,
    const float* __restrict__ bias, float* __restrict__ out) {
  int wv = threadIdx.x >> 6;
  int lane = threadIdx.x & 63;
  int t = blockIdx.x * 4 + wv;  // grid is exactly N_ENT/4
  int half = lane >> 5;         // which edge of the pair
  int sl = lane & 31;
  int elem = sl * 8;            // head = sl>>4
  u16x8 xr8 = *(const u16x8*)(x_r + (size_t)t * HD + elem);
  float xr[8], at[8];
#pragma unroll
  for (int i = 0; i < 8; i++) xr[i] = bf2f(xr8[i]);
  float4 at0 = *(const float4*)(att + elem);
  float4 at1 = *(const float4*)(att + elem + 4);
  at[0] = at0.x; at[1] = at0.y; at[2] = at0.z; at[3] = at0.w;
  at[4] = at1.x; at[5] = at1.y; at[6] = at1.z; at[7] = at1.w;
  int e0 = t * SLOTS;
  int e1 = e0 + cnt[t];         // cnt >= 1 always (query self-edge)
  float denom = 0.f;
  float acc[8];
#pragma unroll
  for (int i = 0; i < 8; i++) acc[i] = 0.f;

  for (int e = e0; e < e1; e += 2) {
    int ee = e + half;
    bool valid = ee < e1;
    unsigned sr = bucket[valid ? ee : e0];
    int s = sr & 0x1FFFF;
    int r = sr >> 17;
    u16x8 xl8 = *(const u16x8*)(x_l + (size_t)s * HD + elem);
    u16x8 er8 = *(const u16x8*)(e_rel + (size_t)r * HD + elem);
    float xl[8];
    float p = 0.f;
#pragma unroll
    for (int i = 0; i < 8; i++) {
      xl[i] = bf2f(xl8[i]);
      float z = xl[i] + xr[i] + bf2f(er8[i]);
      z = z > 0.f ? z : NEG * z;
      p += z * at[i];
    }
    p += __shfl_xor(p, 1, 64);
    p += __shfl_xor(p, 2, 64);
    p += __shfl_xor(p, 4, 64);
    p += __shfl_xor(p, 8, 64);
    float wgt = valid ? __expf(p) : 0.f;
    denom += wgt;
#pragma unroll
    for (int i = 0; i < 8; i++) acc[i] += wgt * xl[i];
  }
  // combine the two edge-halves
  denom += __shfl_xor(denom, 32, 64);
#pragma unroll
  for (int i = 0; i < 8; i++) acc[i] += __shfl_xor(acc[i], 32, 64);
  float inv = 1.f / (denom + 1e-16f);
  float o[8];
#pragma unroll
  for (int i = 0; i < 8; i++) o[i] = acc[i] * inv;
  // combine heads: lane sl (head0) with lane sl^16 (head1), same d
#pragma unroll
  for (int i = 0; i < 8; i++) o[i] += __shfl_xor(o[i], 16, 64);
  if (lane < 16) {
    int d = sl * 8;
    float4 b0 = *(const float4*)(bias + d);
    float4 b1 = *(const float4*)(bias + d + 4);
    *(float4*)(out + (size_t)t * D + d) =
        make_float4(o[0] * 0.5f + b0.x, o[1] * 0.5f + b0.y, o[2] * 0.5f + b0.z, o[3] * 0.5f + b0.w);
    *(float4*)(out + (size_t)t * D + d + 4) =
        make_float4(o[4] * 0.5f + b1.x, o[5] * 0.5f + b1.y, o[6] * 0.5f + b1.z, o[7] * 0.5f + b1.w);
  }
}

extern "C" void kernel_launch(void* const* d_in, const int* in_sizes, int n_in,
                              void* d_out, int out_size, void* d_ws, size_t ws_size,
                              hipStream_t stream) {
  const float* queries = (const float*)d_in[0];
  const float* entities = (const float*)d_in[1];
  const int* edge_index = (const int*)d_in[2];
  const float* relations = (const float*)d_in[3];
  const int* relation_index = (const int*)d_in[4];
  const int* batch = (const int*)d_in[5];
  const float* W_l = (const float*)d_in[6];
  const float* b_l = (const float*)d_in[7];
  const float* W_r = (const float*)d_in[8];
  const float* b_r = (const float*)d_in[9];
  const float* W_ea = (const float*)d_in[10];
  const float* att = (const float*)d_in[11];
  const float* bias = (const float*)d_in[12];
  const float* W_le = (const float*)d_in[13];
  const float* b_le = (const float*)d_in[14];

  float* out_node = (float*)d_out;
  float* out_edge = out_node + (size_t)N_ENT * D;

  char* base = (char*)d_ws;
  size_t off = 0;
  auto take = [&](size_t nbytes) -> void* {
    void* p = base + off;
    off += (nbytes + 255) & ~(size_t)255;
    return p;
  };
  unsigned short* x_l = (unsigned short*)take((size_t)NTOT * HD * sizeof(unsigned short)); // 51.2 MB
  unsigned short* x_r = (unsigned short*)take((size_t)NTOT * HD * sizeof(unsigned short)); // 51.2 MB
  unsigned short* e_rel = (unsigned short*)take((size_t)(RCOUNT + 1) * HD * sizeof(unsigned short));
  unsigned short* Wbf = (unsigned short*)take((size_t)512 * D * sizeof(unsigned short));   // 128 KB
  int* cnt = (int*)take((size_t)CPAD * sizeof(int));                                       // 400 KB
  unsigned int* bucket = (unsigned int*)take((size_t)N_ENT * SLOTS * sizeof(unsigned int)); // 25.6 MB

  k_prep<<<dim3(PREP_NB), dim3(256), 0, stream>>>(W_l, W_r, Wbf, relations, W_ea, W_le, b_le,
                                                  e_rel, out_edge, cnt);
  k_gemm_mfma<<<dim3(GEMM_NB + APP_NB), dim3(256), 0, stream>>>(
      entities, queries, Wbf, b_l, b_r, x_l, x_r,
      edge_index, relation_index, batch, cnt, bucket);
  k_edge<<<dim3(N_ENT / 4), dim3(256), 0, stream>>>(x_l, x_r, e_rel, cnt, bucket, att, bias, out_node);
}